// Round 1
// baseline (1032.960 us; speedup 1.0000x reference)
//
#include <hip/hip_runtime.h>

// APPNP: K iterations of x = (1-ALPHA) * Ahat * x + ALPHA * h0,
// Ahat = D^-1/2 (A + I) D^-1/2, aggregation target = edge_index[1] (dst).
#define N_NODES 100000
#define N_EDGES 1600000
#define D_FEAT  64
#define ALPHA_C 0.8f
#define K_ITER  5

constexpr int SCAN_BLOCK = 256;
constexpr int NB = (N_NODES + SCAN_BLOCK - 1) / SCAN_BLOCK; // 391

// ---------------- setup kernels ----------------

__global__ void hist_k(const int* __restrict__ dst, int* __restrict__ deg, int E) {
    int e = blockIdx.x * blockDim.x + threadIdx.x;
    if (e < E) atomicAdd(&deg[dst[e]], 1);
}

__global__ void dis_k(const int* __restrict__ deg, float* __restrict__ dis, int N) {
    int i = blockIdx.x * blockDim.x + threadIdx.x;
    if (i < N) dis[i] = rsqrtf((float)(deg[i] + 1)); // +1 self-loop
}

// block-level inclusive scan -> exclusive offsets within block + block sums
__global__ void scan1_k(const int* __restrict__ deg, int* __restrict__ rowstart,
                        int* __restrict__ bsum, int N) {
    __shared__ int sh[SCAN_BLOCK];
    int t = threadIdx.x;
    int g = blockIdx.x * SCAN_BLOCK + t;
    int v = (g < N) ? deg[g] : 0;
    sh[t] = v;
    __syncthreads();
    for (int off = 1; off < SCAN_BLOCK; off <<= 1) {
        int y = (t >= off) ? sh[t - off] : 0;
        __syncthreads();
        if (t >= off) sh[t] += y;
        __syncthreads();
    }
    if (g < N) rowstart[g] = sh[t] - v;          // exclusive
    if (t == SCAN_BLOCK - 1) bsum[blockIdx.x] = sh[t];
}

__global__ void scan2_k(int* __restrict__ bsum, int n) {
    __shared__ int sh[512];
    int t = threadIdx.x;
    int v = (t < n) ? bsum[t] : 0;
    sh[t] = v;
    __syncthreads();
    for (int off = 1; off < 512; off <<= 1) {
        int y = (t >= off) ? sh[t - off] : 0;
        __syncthreads();
        if (t >= off) sh[t] += y;
        __syncthreads();
    }
    if (t < n) bsum[t] = sh[t] - v;              // exclusive
}

__global__ void scan3_k(int* __restrict__ rowstart, int* __restrict__ cursor,
                        const int* __restrict__ bsum, int N) {
    int g = blockIdx.x * SCAN_BLOCK + threadIdx.x;
    if (g < N) {
        int v = rowstart[g] + bsum[blockIdx.x];
        rowstart[g] = v;
        cursor[g]   = v;
    }
    if (g == 0) rowstart[N_NODES] = N_EDGES;
}

__global__ void fill_k(const int* __restrict__ src, const int* __restrict__ dst,
                       int* __restrict__ cursor, int* __restrict__ col,
                       float* __restrict__ wgt, const float* __restrict__ dis, int E) {
    int e = blockIdx.x * blockDim.x + threadIdx.x;
    if (e < E) {
        int s = src[e], d = dst[e];
        int p = atomicAdd(&cursor[d], 1);
        col[p] = s;
        wgt[p] = dis[s] * dis[d];
    }
}

// ---------------- propagation ----------------
// one wave (64 lanes) per row; lane = feature index. Row is wave-uniform,
// so col/wgt loads are scalar broadcasts; x gathers are coalesced 256B rows.
__global__ __launch_bounds__(256) void spmm_k(
    const float* __restrict__ xin, const float* __restrict__ h0,
    float* __restrict__ xout, const int* __restrict__ rowstart,
    const int* __restrict__ col, const float* __restrict__ wgt,
    const float* __restrict__ dis, int N) {
    int row  = blockIdx.x * 4 + (threadIdx.x >> 6);
    int lane = threadIdx.x & 63;
    if (row >= N) return;
    int s = rowstart[row];
    int e = rowstart[row + 1];
    float d  = dis[row];
    float acc = d * d * xin[row * D_FEAT + lane];   // self-loop term
    for (int j = s; j < e; ++j) {
        int   c = col[j];
        float w = wgt[j];
        acc += w * xin[c * D_FEAT + lane];
    }
    xout[row * D_FEAT + lane] =
        ALPHA_C * h0[row * D_FEAT + lane] + (1.0f - ALPHA_C) * acc;
}

// ---------------- launch ----------------

extern "C" void kernel_launch(void* const* d_in, const int* in_sizes, int n_in,
                              void* d_out, int out_size, void* d_ws, size_t ws_size,
                              hipStream_t stream) {
    const float* x   = (const float*)d_in[0];
    const int*   ei  = (const int*)d_in[1];
    const int*   src = ei;            // edge_index[0]
    const int*   dst = ei + N_EDGES;  // edge_index[1]
    float*       out = (float*)d_out;

    char* ws = (char*)d_ws;
    size_t off = 0;
    auto alloc = [&](size_t bytes) -> void* {
        void* p = ws + off;
        off = (off + bytes + 255) & ~(size_t)255;
        return p;
    };
    int*   deg      = (int*)  alloc((size_t)N_NODES * 4);
    int*   rowstart = (int*)  alloc((size_t)(N_NODES + 1) * 4);
    int*   cursor   = (int*)  alloc((size_t)N_NODES * 4);
    int*   bsum     = (int*)  alloc((size_t)NB * 4);
    float* dis      = (float*)alloc((size_t)N_NODES * 4);
    int*   col      = (int*)  alloc((size_t)N_EDGES * 4);
    float* wgt      = (float*)alloc((size_t)N_EDGES * 4);
    float* bufA     = (float*)alloc((size_t)N_NODES * D_FEAT * 4);

    hipMemsetAsync(deg, 0, (size_t)N_NODES * 4, stream);

    int eb = (N_EDGES + 255) / 256;
    int nb = (N_NODES + 255) / 256;
    hist_k <<<eb, 256, 0, stream>>>(dst, deg, N_EDGES);
    dis_k  <<<nb, 256, 0, stream>>>(deg, dis, N_NODES);
    scan1_k<<<NB, SCAN_BLOCK, 0, stream>>>(deg, rowstart, bsum, N_NODES);
    scan2_k<<<1, 512, 0, stream>>>(bsum, NB);
    scan3_k<<<NB, SCAN_BLOCK, 0, stream>>>(rowstart, cursor, bsum, N_NODES);
    fill_k <<<eb, 256, 0, stream>>>(src, dst, cursor, col, wgt, dis, N_EDGES);

    // K=5 ping-pong: x -> out -> bufA -> out -> bufA -> out
    int grid = (N_NODES + 3) / 4;
    spmm_k<<<grid, 256, 0, stream>>>(x,    x, out,  rowstart, col, wgt, dis, N_NODES);
    spmm_k<<<grid, 256, 0, stream>>>(out,  x, bufA, rowstart, col, wgt, dis, N_NODES);
    spmm_k<<<grid, 256, 0, stream>>>(bufA, x, out,  rowstart, col, wgt, dis, N_NODES);
    spmm_k<<<grid, 256, 0, stream>>>(out,  x, bufA, rowstart, col, wgt, dis, N_NODES);
    spmm_k<<<grid, 256, 0, stream>>>(bufA, x, out,  rowstart, col, wgt, dis, N_NODES);
}

// Round 2
// 569.029 us; speedup vs baseline: 1.8153x; 1.8153x over previous
//
#include <hip/hip_runtime.h>

// APPNP: K iterations of x = (1-ALPHA) * Ahat * x + ALPHA * h0,
// Ahat = D^-1/2 (A + I) D^-1/2, aggregation target = edge_index[1] (dst).
#define N_NODES 100000
#define N_EDGES 1600000
#define D_FEAT  64
#define ALPHA_C 0.8f

constexpr int SCAN_BLOCK = 256;
constexpr int NB = (N_NODES + SCAN_BLOCK - 1) / SCAN_BLOCK; // 391

// ---------------- setup kernels ----------------

__global__ void hist_k(const int* __restrict__ dst, int* __restrict__ deg, int E) {
    int e = blockIdx.x * blockDim.x + threadIdx.x;
    if (e < E) atomicAdd(&deg[dst[e]], 1);
}

__global__ void dis_k(const int* __restrict__ deg, float* __restrict__ dis, int N) {
    int i = blockIdx.x * blockDim.x + threadIdx.x;
    if (i < N) dis[i] = rsqrtf((float)(deg[i] + 1)); // +1 self-loop
}

// block-level inclusive scan -> exclusive offsets within block + block sums
__global__ void scan1_k(const int* __restrict__ deg, int* __restrict__ rowstart,
                        int* __restrict__ bsum, int N) {
    __shared__ int sh[SCAN_BLOCK];
    int t = threadIdx.x;
    int g = blockIdx.x * SCAN_BLOCK + t;
    int v = (g < N) ? deg[g] : 0;
    sh[t] = v;
    __syncthreads();
    for (int off = 1; off < SCAN_BLOCK; off <<= 1) {
        int y = (t >= off) ? sh[t - off] : 0;
        __syncthreads();
        if (t >= off) sh[t] += y;
        __syncthreads();
    }
    if (g < N) rowstart[g] = sh[t] - v;          // exclusive
    if (t == SCAN_BLOCK - 1) bsum[blockIdx.x] = sh[t];
}

__global__ void scan2_k(int* __restrict__ bsum, int n) {
    __shared__ int sh[512];
    int t = threadIdx.x;
    int v = (t < n) ? bsum[t] : 0;
    sh[t] = v;
    __syncthreads();
    for (int off = 1; off < 512; off <<= 1) {
        int y = (t >= off) ? sh[t - off] : 0;
        __syncthreads();
        if (t >= off) sh[t] += y;
        __syncthreads();
    }
    if (t < n) bsum[t] = sh[t] - v;              // exclusive
}

__global__ void scan3_k(int* __restrict__ rowstart, int* __restrict__ cursor,
                        const int* __restrict__ bsum, int N) {
    int g = blockIdx.x * SCAN_BLOCK + threadIdx.x;
    if (g < N) {
        int v = rowstart[g] + bsum[blockIdx.x];
        rowstart[g] = v;
        cursor[g]   = v;
    }
    if (g == 0) rowstart[N_NODES] = N_EDGES;
}

// col+wgt fused: cw[p].x = src node, cw[p].y = weight bits
__global__ void fill_k(const int* __restrict__ src, const int* __restrict__ dst,
                       int* __restrict__ cursor, int2* __restrict__ cw,
                       const float* __restrict__ dis, int E) {
    int e = blockIdx.x * blockDim.x + threadIdx.x;
    if (e < E) {
        int s = src[e], d = dst[e];
        int p = atomicAdd(&cursor[d], 1);
        int2 v;
        v.x = s;
        v.y = __float_as_int(dis[s] * dis[d]);
        cw[p] = v;
    }
}

// ---------------- propagation ----------------
// One wave per row. Lane layout: grp = lane>>4 (neighbor slot 0..3),
// f = lane&15 (float4 chunk of the 64-float feature row).
// Each iteration a wave processes up to 8 neighbors (2-deep unroll x 4 slots),
// each as a 16B dwordx4 gather. Cross-slot reduce via shfl_xor(16|32).
__global__ __launch_bounds__(256) void spmm_k(
    const float4* __restrict__ xin4, const float4* __restrict__ h04,
    float4* __restrict__ xout4, const int* __restrict__ rowstart,
    const int2* __restrict__ cw, const float* __restrict__ dis, int N) {
    int row  = blockIdx.x * 4 + (threadIdx.x >> 6);
    if (row >= N) return;
    int lane = threadIdx.x & 63;
    int grp  = lane >> 4;
    int f    = lane & 15;

    int s = rowstart[row];
    int e = rowstart[row + 1];

    float4 acc0 = {0.f, 0.f, 0.f, 0.f};
    float4 acc1 = {0.f, 0.f, 0.f, 0.f};

    int jj = s + grp;
    // pairs (jj, jj+4) both valid while jj+4 < e
    for (; jj + 4 < e; jj += 8) {
        int2 cw0 = cw[jj];
        int2 cw1 = cw[jj + 4];
        float w0 = __int_as_float(cw0.y);
        float w1 = __int_as_float(cw1.y);
        float4 a = xin4[(size_t)cw0.x * 16 + f];
        float4 b = xin4[(size_t)cw1.x * 16 + f];
        acc0.x += w0 * a.x; acc0.y += w0 * a.y; acc0.z += w0 * a.z; acc0.w += w0 * a.w;
        acc1.x += w1 * b.x; acc1.y += w1 * b.y; acc1.z += w1 * b.z; acc1.w += w1 * b.w;
    }
    if (jj < e) {
        int2 cw0 = cw[jj];
        float w0 = __int_as_float(cw0.y);
        float4 a = xin4[(size_t)cw0.x * 16 + f];
        acc0.x += w0 * a.x; acc0.y += w0 * a.y; acc0.z += w0 * a.z; acc0.w += w0 * a.w;
    }
    acc0.x += acc1.x; acc0.y += acc1.y; acc0.z += acc1.z; acc0.w += acc1.w;

    // self-loop term on slot 0 only (so the cross-slot reduce counts it once)
    if (grp == 0) {
        float d  = dis[row];
        float d2 = d * d;
        float4 sx = xin4[(size_t)row * 16 + f];
        acc0.x += d2 * sx.x; acc0.y += d2 * sx.y; acc0.z += d2 * sx.z; acc0.w += d2 * sx.w;
    }

    // reduce across the 4 neighbor slots (lanes differing in bits 4,5)
    #pragma unroll
    for (int off = 16; off <= 32; off <<= 1) {
        acc0.x += __shfl_xor(acc0.x, off);
        acc0.y += __shfl_xor(acc0.y, off);
        acc0.z += __shfl_xor(acc0.z, off);
        acc0.w += __shfl_xor(acc0.w, off);
    }

    if (grp == 0) {
        float4 h = h04[(size_t)row * 16 + f];
        float4 o;
        o.x = ALPHA_C * h.x + (1.0f - ALPHA_C) * acc0.x;
        o.y = ALPHA_C * h.y + (1.0f - ALPHA_C) * acc0.y;
        o.z = ALPHA_C * h.z + (1.0f - ALPHA_C) * acc0.z;
        o.w = ALPHA_C * h.w + (1.0f - ALPHA_C) * acc0.w;
        xout4[(size_t)row * 16 + f] = o;
    }
}

// ---------------- launch ----------------

extern "C" void kernel_launch(void* const* d_in, const int* in_sizes, int n_in,
                              void* d_out, int out_size, void* d_ws, size_t ws_size,
                              hipStream_t stream) {
    const float* x   = (const float*)d_in[0];
    const int*   ei  = (const int*)d_in[1];
    const int*   src = ei;            // edge_index[0]
    const int*   dst = ei + N_EDGES;  // edge_index[1]
    float*       out = (float*)d_out;

    char* ws = (char*)d_ws;
    size_t off = 0;
    auto alloc = [&](size_t bytes) -> void* {
        void* p = ws + off;
        off = (off + bytes + 255) & ~(size_t)255;
        return p;
    };
    int*   deg      = (int*)  alloc((size_t)N_NODES * 4);
    int*   rowstart = (int*)  alloc((size_t)(N_NODES + 1) * 4);
    int*   cursor   = (int*)  alloc((size_t)N_NODES * 4);
    int*   bsum     = (int*)  alloc((size_t)NB * 4);
    float* dis      = (float*)alloc((size_t)N_NODES * 4);
    int2*  cw       = (int2*) alloc((size_t)N_EDGES * 8);
    float* bufA     = (float*)alloc((size_t)N_NODES * D_FEAT * 4);

    hipMemsetAsync(deg, 0, (size_t)N_NODES * 4, stream);

    int eb = (N_EDGES + 255) / 256;
    int nb = (N_NODES + 255) / 256;
    hist_k <<<eb, 256, 0, stream>>>(dst, deg, N_EDGES);
    dis_k  <<<nb, 256, 0, stream>>>(deg, dis, N_NODES);
    scan1_k<<<NB, SCAN_BLOCK, 0, stream>>>(deg, rowstart, bsum, N_NODES);
    scan2_k<<<1, 512, 0, stream>>>(bsum, NB);
    scan3_k<<<NB, SCAN_BLOCK, 0, stream>>>(rowstart, cursor, bsum, N_NODES);
    fill_k <<<eb, 256, 0, stream>>>(src, dst, cursor, cw, dis, N_EDGES);

    // K=5 ping-pong: x -> out -> bufA -> out -> bufA -> out
    int grid = (N_NODES + 3) / 4;
    const float4* x4   = (const float4*)x;
    float4*       out4 = (float4*)out;
    float4*       a4   = (float4*)bufA;
    spmm_k<<<grid, 256, 0, stream>>>(x4,                  x4, out4, rowstart, cw, dis, N_NODES);
    spmm_k<<<grid, 256, 0, stream>>>((const float4*)out4, x4, a4,   rowstart, cw, dis, N_NODES);
    spmm_k<<<grid, 256, 0, stream>>>((const float4*)a4,   x4, out4, rowstart, cw, dis, N_NODES);
    spmm_k<<<grid, 256, 0, stream>>>((const float4*)out4, x4, a4,   rowstart, cw, dis, N_NODES);
    spmm_k<<<grid, 256, 0, stream>>>((const float4*)a4,   x4, out4, rowstart, cw, dis, N_NODES);
}

// Round 3
// 471.882 us; speedup vs baseline: 2.1890x; 1.2059x over previous
//
#include <hip/hip_runtime.h>

// APPNP: K=5 iterations of x = 0.2 * Ahat * x + 0.8 * h0.
// R3: intermediate x iterates stored in bf16 (halves gather traffic);
// h0 kept fp32 so the 0.8-weighted teleport term is exact each iteration.
#define N_NODES 100000
#define N_EDGES 1600000
#define D_FEAT  64
#define ALPHA_C 0.8f
#define BETA_C  0.2f

constexpr int SCAN_BLOCK = 256;
constexpr int NB = (N_NODES + SCAN_BLOCK - 1) / SCAN_BLOCK; // 391

// ---------------- setup kernels (unchanged from R2) ----------------

__global__ void hist_k(const int* __restrict__ dst, int* __restrict__ deg, int E) {
    int e = blockIdx.x * blockDim.x + threadIdx.x;
    if (e < E) atomicAdd(&deg[dst[e]], 1);
}

__global__ void dis_k(const int* __restrict__ deg, float* __restrict__ dis, int N) {
    int i = blockIdx.x * blockDim.x + threadIdx.x;
    if (i < N) dis[i] = rsqrtf((float)(deg[i] + 1)); // +1 self-loop
}

__global__ void scan1_k(const int* __restrict__ deg, int* __restrict__ rowstart,
                        int* __restrict__ bsum, int N) {
    __shared__ int sh[SCAN_BLOCK];
    int t = threadIdx.x;
    int g = blockIdx.x * SCAN_BLOCK + t;
    int v = (g < N) ? deg[g] : 0;
    sh[t] = v;
    __syncthreads();
    for (int off = 1; off < SCAN_BLOCK; off <<= 1) {
        int y = (t >= off) ? sh[t - off] : 0;
        __syncthreads();
        if (t >= off) sh[t] += y;
        __syncthreads();
    }
    if (g < N) rowstart[g] = sh[t] - v;
    if (t == SCAN_BLOCK - 1) bsum[blockIdx.x] = sh[t];
}

__global__ void scan2_k(int* __restrict__ bsum, int n) {
    __shared__ int sh[512];
    int t = threadIdx.x;
    int v = (t < n) ? bsum[t] : 0;
    sh[t] = v;
    __syncthreads();
    for (int off = 1; off < 512; off <<= 1) {
        int y = (t >= off) ? sh[t - off] : 0;
        __syncthreads();
        if (t >= off) sh[t] += y;
        __syncthreads();
    }
    if (t < n) bsum[t] = sh[t] - v;
}

__global__ void scan3_k(int* __restrict__ rowstart, int* __restrict__ cursor,
                        const int* __restrict__ bsum, int N) {
    int g = blockIdx.x * SCAN_BLOCK + threadIdx.x;
    if (g < N) {
        int v = rowstart[g] + bsum[blockIdx.x];
        rowstart[g] = v;
        cursor[g]   = v;
    }
    if (g == 0) rowstart[N_NODES] = N_EDGES;
}

__global__ void fill_k(const int* __restrict__ src, const int* __restrict__ dst,
                       int* __restrict__ cursor, int2* __restrict__ cw,
                       const float* __restrict__ dis, int E) {
    int e = blockIdx.x * blockDim.x + threadIdx.x;
    if (e < E) {
        int s = src[e], d = dst[e];
        int p = atomicAdd(&cursor[d], 1);
        int2 v;
        v.x = s;
        v.y = __float_as_int(dis[s] * dis[d]);
        cw[p] = v;
    }
}

// ---------------- bf16 helpers ----------------

__device__ inline unsigned pack_bf16_rne(float a, float b) {
    unsigned ua = __float_as_uint(a);
    unsigned ub = __float_as_uint(b);
    ua = (ua + 0x7FFFu + ((ua >> 16) & 1u)) >> 16;
    ub = (ub + 0x7FFFu + ((ub >> 16) & 1u)) >> 16;
    return ua | (ub << 16);
}

__device__ inline void bf16x8_fma(const uint4 u, float w, float* acc) {
    acc[0] += w * __uint_as_float(u.x << 16);
    acc[1] += w * __uint_as_float(u.x & 0xFFFF0000u);
    acc[2] += w * __uint_as_float(u.y << 16);
    acc[3] += w * __uint_as_float(u.y & 0xFFFF0000u);
    acc[4] += w * __uint_as_float(u.z << 16);
    acc[5] += w * __uint_as_float(u.z & 0xFFFF0000u);
    acc[6] += w * __uint_as_float(u.w << 16);
    acc[7] += w * __uint_as_float(u.w & 0xFFFF0000u);
}

// fp32 x -> bf16 rows (seed buffer)
__global__ void cvt_k(const float4* __restrict__ x4, uint2* __restrict__ xb, int n4) {
    int t = blockIdx.x * blockDim.x + threadIdx.x;
    if (t < n4) {
        float4 v = x4[t];
        uint2 o;
        o.x = pack_bf16_rne(v.x, v.y);
        o.y = pack_bf16_rne(v.z, v.w);
        xb[t] = o;
    }
}

// ---------------- propagation ----------------
// One wave per row. slot = lane>>3 (8 neighbor slots), f = lane&7
// (16B = 8 bf16 feats per lane). 16 neighbors per loop iteration.
// Butterfly shfl_xor reduce leaves the full row sum in every lane.
template <bool OUT_BF16>
__global__ __launch_bounds__(256) void spmm_k(
    const uint4* __restrict__ xin,    // bf16 rows: row*8 + f
    const float4* __restrict__ h04,   // fp32 h0:   row*16 + chunk
    void* __restrict__ out_,
    const int* __restrict__ rowstart,
    const int2* __restrict__ cw, const float* __restrict__ dis, int N) {
    int row = blockIdx.x * 4 + (threadIdx.x >> 6);
    if (row >= N) return;
    int lane = threadIdx.x & 63;
    int slot = lane >> 3;
    int f    = lane & 7;

    int s = rowstart[row];
    int e = rowstart[row + 1];

    float acc0[8] = {0,0,0,0,0,0,0,0};
    float acc1[8] = {0,0,0,0,0,0,0,0};

    int jj = s + slot;
    for (; jj + 8 < e; jj += 16) {
        int2 c0 = cw[jj];
        int2 c1 = cw[jj + 8];
        uint4 a = xin[(size_t)c0.x * 8 + f];
        uint4 b = xin[(size_t)c1.x * 8 + f];
        bf16x8_fma(a, __int_as_float(c0.y), acc0);
        bf16x8_fma(b, __int_as_float(c1.y), acc1);
    }
    if (jj < e) {
        int2 c0 = cw[jj];
        uint4 a = xin[(size_t)c0.x * 8 + f];
        bf16x8_fma(a, __int_as_float(c0.y), acc0);
    }
    #pragma unroll
    for (int i = 0; i < 8; ++i) acc0[i] += acc1[i];

    // self-loop term, counted once (slot 0 only, before the reduce)
    if (slot == 0) {
        float d = dis[row];
        uint4 sx = xin[(size_t)row * 8 + f];
        bf16x8_fma(sx, d * d, acc0);
    }

    #pragma unroll
    for (int m = 8; m <= 32; m <<= 1) {
        #pragma unroll
        for (int i = 0; i < 8; ++i) acc0[i] += __shfl_xor(acc0[i], m);
    }

    if (OUT_BF16) {
        if (slot == 0) {
            float4 ha = h04[(size_t)row * 16 + 2 * f];
            float4 hb = h04[(size_t)row * 16 + 2 * f + 1];
            uint4 st;
            st.x = pack_bf16_rne(ALPHA_C * ha.x + BETA_C * acc0[0],
                                 ALPHA_C * ha.y + BETA_C * acc0[1]);
            st.y = pack_bf16_rne(ALPHA_C * ha.z + BETA_C * acc0[2],
                                 ALPHA_C * ha.w + BETA_C * acc0[3]);
            st.z = pack_bf16_rne(ALPHA_C * hb.x + BETA_C * acc0[4],
                                 ALPHA_C * hb.y + BETA_C * acc0[5]);
            st.w = pack_bf16_rne(ALPHA_C * hb.z + BETA_C * acc0[6],
                                 ALPHA_C * hb.w + BETA_C * acc0[7]);
            ((uint4*)out_)[(size_t)row * 8 + f] = st;
        }
    } else {
        if (slot < 2) {
            int chunk = f * 2 + slot;           // 16 lanes cover 16 float4 chunks
            int b = slot * 4;
            float4 h = h04[(size_t)row * 16 + chunk];
            float4 o;
            o.x = ALPHA_C * h.x + BETA_C * acc0[b + 0];
            o.y = ALPHA_C * h.y + BETA_C * acc0[b + 1];
            o.z = ALPHA_C * h.z + BETA_C * acc0[b + 2];
            o.w = ALPHA_C * h.w + BETA_C * acc0[b + 3];
            ((float4*)out_)[(size_t)row * 16 + chunk] = o;
        }
    }
}

// ---------------- launch ----------------

extern "C" void kernel_launch(void* const* d_in, const int* in_sizes, int n_in,
                              void* d_out, int out_size, void* d_ws, size_t ws_size,
                              hipStream_t stream) {
    const float* x   = (const float*)d_in[0];
    const int*   ei  = (const int*)d_in[1];
    const int*   src = ei;            // edge_index[0]
    const int*   dst = ei + N_EDGES;  // edge_index[1]

    char* ws = (char*)d_ws;
    size_t off = 0;
    auto alloc = [&](size_t bytes) -> void* {
        void* p = ws + off;
        off = (off + bytes + 255) & ~(size_t)255;
        return p;
    };
    int*   deg      = (int*)  alloc((size_t)N_NODES * 4);
    int*   rowstart = (int*)  alloc((size_t)(N_NODES + 1) * 4);
    int*   cursor   = (int*)  alloc((size_t)N_NODES * 4);
    int*   bsum     = (int*)  alloc((size_t)NB * 4);
    float* dis      = (float*)alloc((size_t)N_NODES * 4);
    int2*  cw       = (int2*) alloc((size_t)N_EDGES * 8);
    void*  xb0      = alloc((size_t)N_NODES * D_FEAT * 2);   // bf16 iterate
    void*  xb1      = alloc((size_t)N_NODES * D_FEAT * 2);   // bf16 iterate

    hipMemsetAsync(deg, 0, (size_t)N_NODES * 4, stream);

    int eb = (N_EDGES + 255) / 256;
    int nb = (N_NODES + 255) / 256;
    hist_k <<<eb, 256, 0, stream>>>(dst, deg, N_EDGES);
    dis_k  <<<nb, 256, 0, stream>>>(deg, dis, N_NODES);
    scan1_k<<<NB, SCAN_BLOCK, 0, stream>>>(deg, rowstart, bsum, N_NODES);
    scan2_k<<<1, 512, 0, stream>>>(bsum, NB);
    scan3_k<<<NB, SCAN_BLOCK, 0, stream>>>(rowstart, cursor, bsum, N_NODES);
    fill_k <<<eb, 256, 0, stream>>>(src, dst, cursor, cw, dis, N_EDGES);

    // seed bf16 iterate from fp32 x
    int n4 = N_NODES * D_FEAT / 4;
    cvt_k<<<(n4 + 255) / 256, 256, 0, stream>>>((const float4*)x, (uint2*)xb0, n4);

    const float4* h0 = (const float4*)x;
    int grid = (N_NODES + 3) / 4;
    // 5 iterations: bf16 ping-pong, final writes fp32 to d_out
    spmm_k<true ><<<grid, 256, 0, stream>>>((const uint4*)xb0, h0, xb1,  rowstart, cw, dis, N_NODES);
    spmm_k<true ><<<grid, 256, 0, stream>>>((const uint4*)xb1, h0, xb0,  rowstart, cw, dis, N_NODES);
    spmm_k<true ><<<grid, 256, 0, stream>>>((const uint4*)xb0, h0, xb1,  rowstart, cw, dis, N_NODES);
    spmm_k<true ><<<grid, 256, 0, stream>>>((const uint4*)xb1, h0, xb0,  rowstart, cw, dis, N_NODES);
    spmm_k<false><<<grid, 256, 0, stream>>>((const uint4*)xb0, h0, d_out, rowstart, cw, dis, N_NODES);
}

// Round 4
// 451.025 us; speedup vs baseline: 2.2903x; 1.0462x over previous
//
#include <hip/hip_runtime.h>

// APPNP: K=5 iterations of x = 0.2 * Ahat * x + 0.8 * h0.
// R4: z-space iteration (z = dis .* x) -> edge payload is col-only, inner loop
// is pure add. Two-pass LDS-binned CSR build kills fill_k's 101MB
// write-allocate (R3 counter evidence: 8B random scatters -> 64B dirty lines).
#define N_NODES 100000
#define N_EDGES 1600000
#define D_FEAT  64
#define ALPHA_C 0.8f
#define BETA_C  0.2f

#define BSHIFT  10                                   // 1024 nodes per bucket
#define NBUCK   ((N_NODES + 1023) >> BSHIFT)         // 98

constexpr int SCAN_BLOCK = 256;
constexpr int NB = (N_NODES + SCAN_BLOCK - 1) / SCAN_BLOCK; // 391

// ---------------- setup kernels ----------------

__global__ void hist_k(const int* __restrict__ dst, int* __restrict__ deg, int E) {
    int e = blockIdx.x * blockDim.x + threadIdx.x;
    if (e < E) atomicAdd(&deg[dst[e]], 1);
}

__global__ void dis_k(const int* __restrict__ deg, float* __restrict__ dis, int N) {
    int i = blockIdx.x * blockDim.x + threadIdx.x;
    if (i < N) dis[i] = rsqrtf((float)(deg[i] + 1)); // +1 self-loop
}

__global__ void scan1_k(const int* __restrict__ deg, int* __restrict__ rowstart,
                        int* __restrict__ bsum, int N) {
    __shared__ int sh[SCAN_BLOCK];
    int t = threadIdx.x;
    int g = blockIdx.x * SCAN_BLOCK + t;
    int v = (g < N) ? deg[g] : 0;
    sh[t] = v;
    __syncthreads();
    for (int off = 1; off < SCAN_BLOCK; off <<= 1) {
        int y = (t >= off) ? sh[t - off] : 0;
        __syncthreads();
        if (t >= off) sh[t] += y;
        __syncthreads();
    }
    if (g < N) rowstart[g] = sh[t] - v;
    if (t == SCAN_BLOCK - 1) bsum[blockIdx.x] = sh[t];
}

__global__ void scan2_k(int* __restrict__ bsum, int n) {
    __shared__ int sh[512];
    int t = threadIdx.x;
    int v = (t < n) ? bsum[t] : 0;
    sh[t] = v;
    __syncthreads();
    for (int off = 1; off < 512; off <<= 1) {
        int y = (t >= off) ? sh[t - off] : 0;
        __syncthreads();
        if (t >= off) sh[t] += y;
        __syncthreads();
    }
    if (t < n) bsum[t] = sh[t] - v;
}

// finalize rowstart; seed per-bucket global stage cursors at bucket starts
__global__ void scan3_k(int* __restrict__ rowstart, int* __restrict__ gcur,
                        const int* __restrict__ bsum, int N) {
    int g = blockIdx.x * SCAN_BLOCK + threadIdx.x;
    if (g < N) {
        int v = rowstart[g] + bsum[blockIdx.x];
        rowstart[g] = v;
        if ((g & ((1 << BSHIFT) - 1)) == 0) gcur[g >> BSHIFT] = v;
    }
    if (g == 0) rowstart[N_NODES] = N_EDGES;
}

// ---- pass 1: bin edges by dst-bucket into CSR-region-ordered staging ----
// Tile of 2048 edges per block; LDS histogram gives each edge a rank, one
// global atomic per (block,bucket) reserves contiguous space -> stores land
// in ~170B contiguous runs (full cache lines, no write-allocate waste).
__global__ __launch_bounds__(256) void bin1_k(
    const int* __restrict__ src, const int* __restrict__ dst,
    int* __restrict__ gcur, uint2* __restrict__ stage, int E) {
    __shared__ int cnt[NBUCK];
    __shared__ int gbase[NBUCK];
    int t = threadIdx.x;
    for (int i = t; i < NBUCK; i += 256) cnt[i] = 0;
    __syncthreads();
    int base = blockIdx.x * 2048;
    int s[8], d[8], r[8];
    #pragma unroll
    for (int i = 0; i < 8; ++i) {
        int e = base + t + i * 256;
        if (e < E) {
            s[i] = src[e];
            d[i] = dst[e];
            r[i] = atomicAdd(&cnt[d[i] >> BSHIFT], 1);
        }
    }
    __syncthreads();
    for (int i = t; i < NBUCK; i += 256)
        if (cnt[i]) gbase[i] = atomicAdd(&gcur[i], cnt[i]);
    __syncthreads();
    #pragma unroll
    for (int i = 0; i < 8; ++i) {
        int e = base + t + i * 256;
        if (e < E) {
            int b = d[i] >> BSHIFT;
            stage[gbase[b] + r[i]] = make_uint2((unsigned)s[i], (unsigned)d[i]);
        }
    }
}

// ---- pass 2: scatter within bucket. 4 blocks/bucket, each owns a 256-node
// quarter with LDS cursors; scatter window is ~16KB -> L2-resident, full lines.
__global__ __launch_bounds__(256) void bin2_k(
    const uint2* __restrict__ stage, const int* __restrict__ rowstart,
    int* __restrict__ col, int N) {
    int b = blockIdx.x >> 2;
    int q = blockIdx.x & 3;
    int nlo = (b << BSHIFT) + (q << 8);
    __shared__ int cur[256];
    int t = threadIdx.x;
    int node = nlo + t;
    cur[t] = (node < N) ? rowstart[node] : 0;
    __syncthreads();
    int blo = b << BSHIFT;
    int bhi = blo + (1 << BSHIFT); if (bhi > N) bhi = N;
    int slo = rowstart[blo];
    int shi = rowstart[bhi];
    for (int j = slo + t; j < shi; j += 256) {
        uint2 e = stage[j];
        int local = (int)e.y - nlo;
        if ((unsigned)local < 256u) {
            int p = atomicAdd(&cur[local], 1);
            col[p] = (int)e.x;
        }
    }
}

// ---------------- bf16 helpers ----------------

__device__ inline unsigned pack_bf16_rne(float a, float b) {
    unsigned ua = __float_as_uint(a);
    unsigned ub = __float_as_uint(b);
    ua = (ua + 0x7FFFu + ((ua >> 16) & 1u)) >> 16;
    ub = (ub + 0x7FFFu + ((ub >> 16) & 1u)) >> 16;
    return ua | (ub << 16);
}

__device__ inline void bf16x8_add(const uint4 u, float* acc) {
    acc[0] += __uint_as_float(u.x << 16);
    acc[1] += __uint_as_float(u.x & 0xFFFF0000u);
    acc[2] += __uint_as_float(u.y << 16);
    acc[3] += __uint_as_float(u.y & 0xFFFF0000u);
    acc[4] += __uint_as_float(u.z << 16);
    acc[5] += __uint_as_float(u.z & 0xFFFF0000u);
    acc[6] += __uint_as_float(u.w << 16);
    acc[7] += __uint_as_float(u.w & 0xFFFF0000u);
}

// zh0 = dis .* x, packed bf16 (also the seed iterate z0)
__global__ void cvt_k(const float4* __restrict__ x4, const float* __restrict__ dis,
                      uint2* __restrict__ zh, int n4) {
    int t = blockIdx.x * blockDim.x + threadIdx.x;
    if (t < n4) {
        float dd = dis[t >> 4];
        float4 v = x4[t];
        uint2 o;
        o.x = pack_bf16_rne(dd * v.x, dd * v.y);
        o.y = pack_bf16_rne(dd * v.z, dd * v.w);
        zh[t] = o;
    }
}

// ---------------- propagation (z-space) ----------------
// One wave per row; slot = lane>>3 (8 neighbor slots), f = lane&7 (16B of the
// 128B bf16 row). acc = sum of z over N+(row) (pure adds). Intermediate:
// z' = 0.2*dis^2*acc + 0.8*zh0 (bf16). Final: x = 0.2*dis*acc + 0.8*h0 (fp32).
template <bool FINAL>
__global__ __launch_bounds__(256) void spmm_k(
    const uint4* __restrict__ zin, const uint4* __restrict__ zh0,
    const float4* __restrict__ h04, void* __restrict__ out_,
    const int* __restrict__ rowstart, const int* __restrict__ col,
    const float* __restrict__ dis, int N) {
    int row = blockIdx.x * 4 + (threadIdx.x >> 6);
    if (row >= N) return;
    int lane = threadIdx.x & 63;
    int slot = lane >> 3;
    int f    = lane & 7;

    int s = rowstart[row];
    int e = rowstart[row + 1];

    float acc0[8] = {0,0,0,0,0,0,0,0};
    float acc1[8] = {0,0,0,0,0,0,0,0};

    int jj = s + slot;
    for (; jj + 8 < e; jj += 16) {
        int c0 = col[jj];
        int c1 = col[jj + 8];
        uint4 a = zin[(size_t)c0 * 8 + f];
        uint4 b = zin[(size_t)c1 * 8 + f];
        bf16x8_add(a, acc0);
        bf16x8_add(b, acc1);
    }
    if (jj < e) {
        uint4 a = zin[(size_t)col[jj] * 8 + f];
        bf16x8_add(a, acc0);
    }
    #pragma unroll
    for (int i = 0; i < 8; ++i) acc0[i] += acc1[i];

    if (slot == 0) {                       // self-loop term, counted once
        uint4 sx = zin[(size_t)row * 8 + f];
        bf16x8_add(sx, acc0);
    }

    #pragma unroll
    for (int m = 8; m <= 32; m <<= 1) {
        #pragma unroll
        for (int i = 0; i < 8; ++i) acc0[i] += __shfl_xor(acc0[i], m);
    }

    float dd = dis[row];
    if (FINAL) {
        if (slot < 2) {
            float w = BETA_C * dd;
            int chunk = f * 2 + slot;
            int b = slot * 4;
            float4 h = h04[(size_t)row * 16 + chunk];
            float4 o;
            o.x = ALPHA_C * h.x + w * acc0[b + 0];
            o.y = ALPHA_C * h.y + w * acc0[b + 1];
            o.z = ALPHA_C * h.z + w * acc0[b + 2];
            o.w = ALPHA_C * h.w + w * acc0[b + 3];
            ((float4*)out_)[(size_t)row * 16 + chunk] = o;
        }
    } else {
        if (slot == 0) {
            float w = BETA_C * dd * dd;
            uint4 zh = zh0[(size_t)row * 8 + f];
            float hf[8];
            hf[0] = __uint_as_float(zh.x << 16);
            hf[1] = __uint_as_float(zh.x & 0xFFFF0000u);
            hf[2] = __uint_as_float(zh.y << 16);
            hf[3] = __uint_as_float(zh.y & 0xFFFF0000u);
            hf[4] = __uint_as_float(zh.z << 16);
            hf[5] = __uint_as_float(zh.z & 0xFFFF0000u);
            hf[6] = __uint_as_float(zh.w << 16);
            hf[7] = __uint_as_float(zh.w & 0xFFFF0000u);
            uint4 st;
            st.x = pack_bf16_rne(w * acc0[0] + ALPHA_C * hf[0],
                                 w * acc0[1] + ALPHA_C * hf[1]);
            st.y = pack_bf16_rne(w * acc0[2] + ALPHA_C * hf[2],
                                 w * acc0[3] + ALPHA_C * hf[3]);
            st.z = pack_bf16_rne(w * acc0[4] + ALPHA_C * hf[4],
                                 w * acc0[5] + ALPHA_C * hf[5]);
            st.w = pack_bf16_rne(w * acc0[6] + ALPHA_C * hf[6],
                                 w * acc0[7] + ALPHA_C * hf[7]);
            ((uint4*)out_)[(size_t)row * 8 + f] = st;
        }
    }
}

// ---------------- launch ----------------

extern "C" void kernel_launch(void* const* d_in, const int* in_sizes, int n_in,
                              void* d_out, int out_size, void* d_ws, size_t ws_size,
                              hipStream_t stream) {
    const float* x   = (const float*)d_in[0];
    const int*   ei  = (const int*)d_in[1];
    const int*   src = ei;            // edge_index[0]
    const int*   dst = ei + N_EDGES;  // edge_index[1]

    char* ws = (char*)d_ws;
    size_t off = 0;
    auto alloc = [&](size_t bytes) -> void* {
        void* p = ws + off;
        off = (off + bytes + 255) & ~(size_t)255;
        return p;
    };
    int*   deg      = (int*)  alloc((size_t)N_NODES * 4);
    int*   rowstart = (int*)  alloc((size_t)(N_NODES + 1) * 4);
    int*   bsum     = (int*)  alloc((size_t)NB * 4);
    int*   gcur     = (int*)  alloc((size_t)NBUCK * 4);
    float* dis      = (float*)alloc((size_t)N_NODES * 4);
    int*   col      = (int*)  alloc((size_t)N_EDGES * 4);
    void*  zh0      = alloc((size_t)N_NODES * D_FEAT * 2);   // dis.*h0 bf16
    void*  zb0      = alloc((size_t)N_NODES * D_FEAT * 2);   // z iterate
    void*  zb1      = alloc((size_t)N_NODES * D_FEAT * 2);   // z iterate; first
                                                             // written at it2,
                                                             // stage dead by then
    uint2* stage    = (uint2*)zb1;   // aliased: 12.8MB staging for bin1/bin2
    // NOTE: stage needs E*8 = 12.8MB and zb1 is 12.8MB -> exact fit.

    hipMemsetAsync(deg, 0, (size_t)N_NODES * 4, stream);

    int eb = (N_EDGES + 255) / 256;
    int nb = (N_NODES + 255) / 256;
    hist_k <<<eb, 256, 0, stream>>>(dst, deg, N_EDGES);
    dis_k  <<<nb, 256, 0, stream>>>(deg, dis, N_NODES);
    scan1_k<<<NB, SCAN_BLOCK, 0, stream>>>(deg, rowstart, bsum, N_NODES);
    scan2_k<<<1, 512, 0, stream>>>(bsum, NB);
    scan3_k<<<NB, SCAN_BLOCK, 0, stream>>>(rowstart, gcur, bsum, N_NODES);
    bin1_k <<<(N_EDGES + 2047) / 2048, 256, 0, stream>>>(src, dst, gcur, stage, N_EDGES);
    bin2_k <<<NBUCK * 4, 256, 0, stream>>>(stage, rowstart, col, N_NODES);

    int n4 = N_NODES * D_FEAT / 4;
    cvt_k<<<(n4 + 255) / 256, 256, 0, stream>>>((const float4*)x, dis, (uint2*)zh0, n4);

    const float4* h0 = (const float4*)x;
    int grid = (N_NODES + 3) / 4;
    // it1: zh0 -> zb0 ; it2: zb0 -> zb1 (stage dead) ; it3..; it5 final -> d_out
    spmm_k<false><<<grid, 256, 0, stream>>>((const uint4*)zh0, (const uint4*)zh0, h0, zb0,   rowstart, col, dis, N_NODES);
    spmm_k<false><<<grid, 256, 0, stream>>>((const uint4*)zb0, (const uint4*)zh0, h0, zb1,   rowstart, col, dis, N_NODES);
    spmm_k<false><<<grid, 256, 0, stream>>>((const uint4*)zb1, (const uint4*)zh0, h0, zb0,   rowstart, col, dis, N_NODES);
    spmm_k<false><<<grid, 256, 0, stream>>>((const uint4*)zb0, (const uint4*)zh0, h0, zb1,   rowstart, col, dis, N_NODES);
    spmm_k<true ><<<grid, 256, 0, stream>>>((const uint4*)zb1, (const uint4*)zh0, h0, d_out, rowstart, col, dis, N_NODES);
}

// Round 5
// 417.882 us; speedup vs baseline: 2.4719x; 1.0793x over previous
//
#include <hip/hip_runtime.h>

// APPNP: K=5 iterations of x = 0.2 * Ahat * x + 0.8 * h0.
// R5: degree/dis/rowstart computed per-bucket in LDS from the staged edges
// (kills hist_k's 1.6M scattered global atomics -> 50MB HBM write traffic,
// R4 counter evidence). Pipeline: bcount -> bscan -> bin1 -> ndeg -> bin2.
#define N_NODES 100000
#define N_EDGES 1600000
#define D_FEAT  64
#define ALPHA_C 0.8f
#define BETA_C  0.2f

#define BSHIFT  10                                   // 1024 nodes per bucket
#define NBUCK   ((N_NODES + 1023) >> BSHIFT)         // 98

// ---------------- CSR build ----------------

// per-bucket edge counts: LDS histogram (98 counters), one global atomic per
// (block,bucket) -> ~77K aggregated atomics instead of 1.6M scattered.
__global__ __launch_bounds__(256) void bcount_k(const int* __restrict__ dst,
                                                int* __restrict__ bcnt, int E) {
    __shared__ int cnt[NBUCK];
    int t = threadIdx.x;
    for (int i = t; i < NBUCK; i += 256) cnt[i] = 0;
    __syncthreads();
    int base = blockIdx.x * 2048;
    #pragma unroll
    for (int i = 0; i < 8; ++i) {
        int e = base + t + i * 256;
        if (e < E) atomicAdd(&cnt[dst[e] >> BSHIFT], 1);
    }
    __syncthreads();
    for (int i = t; i < NBUCK; i += 256)
        if (cnt[i]) atomicAdd(&bcnt[i], cnt[i]);
}

// single-block exclusive scan of the 98 bucket counts -> bucket bases + cursors
__global__ void bscan_k(const int* __restrict__ bcnt, int* __restrict__ bbase,
                        int* __restrict__ gcur) {
    __shared__ int sh[128];
    int t = threadIdx.x;                 // 128 threads
    int v = (t < NBUCK) ? bcnt[t] : 0;
    sh[t] = v;
    __syncthreads();
    for (int off = 1; off < 128; off <<= 1) {
        int y = (t >= off) ? sh[t - off] : 0;
        __syncthreads();
        if (t >= off) sh[t] += y;
        __syncthreads();
    }
    if (t < NBUCK) {
        int ex = sh[t] - v;
        bbase[t] = ex;
        gcur[t]  = ex;
    }
    if (t == NBUCK - 1) bbase[NBUCK] = sh[t];
}

// bin edges by dst-bucket into bucket-major staging; LDS histogram ranks +
// one global atomic per (block,bucket) -> ~170B contiguous store runs.
__global__ __launch_bounds__(256) void bin1_k(
    const int* __restrict__ src, const int* __restrict__ dst,
    int* __restrict__ gcur, uint2* __restrict__ stage, int E) {
    __shared__ int cnt[NBUCK];
    __shared__ int gbase[NBUCK];
    int t = threadIdx.x;
    for (int i = t; i < NBUCK; i += 256) cnt[i] = 0;
    __syncthreads();
    int base = blockIdx.x * 2048;
    int s[8], d[8], r[8];
    #pragma unroll
    for (int i = 0; i < 8; ++i) {
        int e = base + t + i * 256;
        if (e < E) {
            s[i] = src[e];
            d[i] = dst[e];
            r[i] = atomicAdd(&cnt[d[i] >> BSHIFT], 1);
        }
    }
    __syncthreads();
    for (int i = t; i < NBUCK; i += 256)
        if (cnt[i]) gbase[i] = atomicAdd(&gcur[i], cnt[i]);
    __syncthreads();
    #pragma unroll
    for (int i = 0; i < 8; ++i) {
        int e = base + t + i * 256;
        if (e < E) {
            int b = d[i] >> BSHIFT;
            stage[gbase[b] + r[i]] = make_uint2((unsigned)s[i], (unsigned)d[i]);
        }
    }
}

// one block per bucket: LDS per-node degree histogram over the bucket's staged
// edges, then dis = rsqrt(deg+1) and rowstart = bbase + LDS exclusive scan.
// All global writes are dense/coalesced (replaces hist_k + dis_k + 3 scans).
__global__ __launch_bounds__(256) void ndeg_k(
    const uint2* __restrict__ stage, const int* __restrict__ bbase,
    float* __restrict__ dis, int* __restrict__ rowstart, int N) {
    __shared__ int degl[1024];
    __shared__ int part[256];
    int b = blockIdx.x, t = threadIdx.x;
    int nlo = b << BSHIFT;
    for (int i = t; i < 1024; i += 256) degl[i] = 0;
    __syncthreads();
    int slo = bbase[b], shi = bbase[b + 1];
    for (int j = slo + t; j < shi; j += 256) {
        uint2 e = stage[j];
        atomicAdd(&degl[(int)e.y - nlo], 1);
    }
    __syncthreads();
    int s0 = degl[4 * t], s1 = degl[4 * t + 1], s2 = degl[4 * t + 2], s3 = degl[4 * t + 3];
    int c1 = s0 + s1, c2 = c1 + s2, c3 = c2 + s3;
    part[t] = c3;
    __syncthreads();
    for (int off = 1; off < 256; off <<= 1) {
        int y = (t >= off) ? part[t - off] : 0;
        __syncthreads();
        if (t >= off) part[t] += y;
        __syncthreads();
    }
    int pre = part[t] - c3 + slo;        // exclusive prefix + global base
    int n0 = nlo + 4 * t;
    if (n0     <= N) rowstart[n0]     = pre;
    if (n0 + 1 <= N) rowstart[n0 + 1] = pre + s0;
    if (n0 + 2 <= N) rowstart[n0 + 2] = pre + c1;
    if (n0 + 3 <= N) rowstart[n0 + 3] = pre + c2;
    if (n0     < N) dis[n0]     = rsqrtf((float)(s0 + 1));
    if (n0 + 1 < N) dis[n0 + 1] = rsqrtf((float)(s1 + 1));
    if (n0 + 2 < N) dis[n0 + 2] = rsqrtf((float)(s2 + 1));
    if (n0 + 3 < N) dis[n0 + 3] = rsqrtf((float)(s3 + 1));
}

// scatter within bucket: 4 blocks/bucket, each owns a 256-node quarter with
// LDS cursors; ~16KB scatter window -> full-line writebacks.
__global__ __launch_bounds__(256) void bin2_k(
    const uint2* __restrict__ stage, const int* __restrict__ rowstart,
    int* __restrict__ col, int N) {
    int b = blockIdx.x >> 2;
    int q = blockIdx.x & 3;
    int nlo = (b << BSHIFT) + (q << 8);
    __shared__ int cur[256];
    int t = threadIdx.x;
    int node = nlo + t;
    cur[t] = (node < N) ? rowstart[node] : 0;
    __syncthreads();
    int blo = b << BSHIFT;
    int bhi = blo + (1 << BSHIFT); if (bhi > N) bhi = N;
    int slo = rowstart[blo];
    int shi = rowstart[bhi];
    for (int j = slo + t; j < shi; j += 256) {
        uint2 e = stage[j];
        int local = (int)e.y - nlo;
        if ((unsigned)local < 256u) {
            int p = atomicAdd(&cur[local], 1);
            col[p] = (int)e.x;
        }
    }
}

// ---------------- bf16 helpers ----------------

__device__ inline unsigned pack_bf16_rne(float a, float b) {
    unsigned ua = __float_as_uint(a);
    unsigned ub = __float_as_uint(b);
    ua = (ua + 0x7FFFu + ((ua >> 16) & 1u)) >> 16;
    ub = (ub + 0x7FFFu + ((ub >> 16) & 1u)) >> 16;
    return ua | (ub << 16);
}

__device__ inline void bf16x8_add(const uint4 u, float* acc) {
    acc[0] += __uint_as_float(u.x << 16);
    acc[1] += __uint_as_float(u.x & 0xFFFF0000u);
    acc[2] += __uint_as_float(u.y << 16);
    acc[3] += __uint_as_float(u.y & 0xFFFF0000u);
    acc[4] += __uint_as_float(u.z << 16);
    acc[5] += __uint_as_float(u.z & 0xFFFF0000u);
    acc[6] += __uint_as_float(u.w << 16);
    acc[7] += __uint_as_float(u.w & 0xFFFF0000u);
}

// zh0 = dis .* x, packed bf16 (also the seed iterate z0)
__global__ void cvt_k(const float4* __restrict__ x4, const float* __restrict__ dis,
                      uint2* __restrict__ zh, int n4) {
    int t = blockIdx.x * blockDim.x + threadIdx.x;
    if (t < n4) {
        float dd = dis[t >> 4];
        float4 v = x4[t];
        uint2 o;
        o.x = pack_bf16_rne(dd * v.x, dd * v.y);
        o.y = pack_bf16_rne(dd * v.z, dd * v.w);
        zh[t] = o;
    }
}

// ---------------- propagation (z-space) ----------------
template <bool FINAL>
__global__ __launch_bounds__(256) void spmm_k(
    const uint4* __restrict__ zin, const uint4* __restrict__ zh0,
    const float4* __restrict__ h04, void* __restrict__ out_,
    const int* __restrict__ rowstart, const int* __restrict__ col,
    const float* __restrict__ dis, int N) {
    int row = blockIdx.x * 4 + (threadIdx.x >> 6);
    if (row >= N) return;
    int lane = threadIdx.x & 63;
    int slot = lane >> 3;
    int f    = lane & 7;

    int s = rowstart[row];
    int e = rowstart[row + 1];

    float acc0[8] = {0,0,0,0,0,0,0,0};
    float acc1[8] = {0,0,0,0,0,0,0,0};

    int jj = s + slot;
    for (; jj + 8 < e; jj += 16) {
        int c0 = col[jj];
        int c1 = col[jj + 8];
        uint4 a = zin[(size_t)c0 * 8 + f];
        uint4 b = zin[(size_t)c1 * 8 + f];
        bf16x8_add(a, acc0);
        bf16x8_add(b, acc1);
    }
    if (jj < e) {
        uint4 a = zin[(size_t)col[jj] * 8 + f];
        bf16x8_add(a, acc0);
    }
    #pragma unroll
    for (int i = 0; i < 8; ++i) acc0[i] += acc1[i];

    if (slot == 0) {                       // self-loop term, counted once
        uint4 sx = zin[(size_t)row * 8 + f];
        bf16x8_add(sx, acc0);
    }

    #pragma unroll
    for (int m = 8; m <= 32; m <<= 1) {
        #pragma unroll
        for (int i = 0; i < 8; ++i) acc0[i] += __shfl_xor(acc0[i], m);
    }

    float dd = dis[row];
    if (FINAL) {
        if (slot < 2) {
            float w = BETA_C * dd;
            int chunk = f * 2 + slot;
            int b = slot * 4;
            float4 h = h04[(size_t)row * 16 + chunk];
            float4 o;
            o.x = ALPHA_C * h.x + w * acc0[b + 0];
            o.y = ALPHA_C * h.y + w * acc0[b + 1];
            o.z = ALPHA_C * h.z + w * acc0[b + 2];
            o.w = ALPHA_C * h.w + w * acc0[b + 3];
            ((float4*)out_)[(size_t)row * 16 + chunk] = o;
        }
    } else {
        if (slot == 0) {
            float w = BETA_C * dd * dd;
            uint4 zh = zh0[(size_t)row * 8 + f];
            float hf[8];
            hf[0] = __uint_as_float(zh.x << 16);
            hf[1] = __uint_as_float(zh.x & 0xFFFF0000u);
            hf[2] = __uint_as_float(zh.y << 16);
            hf[3] = __uint_as_float(zh.y & 0xFFFF0000u);
            hf[4] = __uint_as_float(zh.z << 16);
            hf[5] = __uint_as_float(zh.z & 0xFFFF0000u);
            hf[6] = __uint_as_float(zh.w << 16);
            hf[7] = __uint_as_float(zh.w & 0xFFFF0000u);
            uint4 st;
            st.x = pack_bf16_rne(w * acc0[0] + ALPHA_C * hf[0],
                                 w * acc0[1] + ALPHA_C * hf[1]);
            st.y = pack_bf16_rne(w * acc0[2] + ALPHA_C * hf[2],
                                 w * acc0[3] + ALPHA_C * hf[3]);
            st.z = pack_bf16_rne(w * acc0[4] + ALPHA_C * hf[4],
                                 w * acc0[5] + ALPHA_C * hf[5]);
            st.w = pack_bf16_rne(w * acc0[6] + ALPHA_C * hf[6],
                                 w * acc0[7] + ALPHA_C * hf[7]);
            ((uint4*)out_)[(size_t)row * 8 + f] = st;
        }
    }
}

// ---------------- launch ----------------

extern "C" void kernel_launch(void* const* d_in, const int* in_sizes, int n_in,
                              void* d_out, int out_size, void* d_ws, size_t ws_size,
                              hipStream_t stream) {
    const float* x   = (const float*)d_in[0];
    const int*   ei  = (const int*)d_in[1];
    const int*   src = ei;            // edge_index[0]
    const int*   dst = ei + N_EDGES;  // edge_index[1]

    char* ws = (char*)d_ws;
    size_t off = 0;
    auto alloc = [&](size_t bytes) -> void* {
        void* p = ws + off;
        off = (off + bytes + 255) & ~(size_t)255;
        return p;
    };
    int*   bcnt     = (int*)  alloc((size_t)NBUCK * 4);
    int*   bbase    = (int*)  alloc((size_t)(NBUCK + 1) * 4);
    int*   gcur     = (int*)  alloc((size_t)NBUCK * 4);
    int*   rowstart = (int*)  alloc((size_t)(N_NODES + 1) * 4);
    float* dis      = (float*)alloc((size_t)N_NODES * 4);
    int*   col      = (int*)  alloc((size_t)N_EDGES * 4);
    void*  zh0      = alloc((size_t)N_NODES * D_FEAT * 2);   // dis.*h0 bf16
    void*  zb0      = alloc((size_t)N_NODES * D_FEAT * 2);   // z iterate
    void*  zb1      = alloc((size_t)N_NODES * D_FEAT * 2);   // z iterate; first
                                                             // written at it2,
                                                             // stage dead by then
    uint2* stage    = (uint2*)zb1;   // aliased: 12.8MB staging (E*8 == N*64*2)

    hipMemsetAsync(bcnt, 0, (size_t)NBUCK * 4, stream);

    int eb2 = (N_EDGES + 2047) / 2048;
    bcount_k<<<eb2, 256, 0, stream>>>(dst, bcnt, N_EDGES);
    bscan_k <<<1, 128, 0, stream>>>(bcnt, bbase, gcur);
    bin1_k  <<<eb2, 256, 0, stream>>>(src, dst, gcur, stage, N_EDGES);
    ndeg_k  <<<NBUCK, 256, 0, stream>>>(stage, bbase, dis, rowstart, N_NODES);
    bin2_k  <<<NBUCK * 4, 256, 0, stream>>>(stage, rowstart, col, N_NODES);

    int n4 = N_NODES * D_FEAT / 4;
    cvt_k<<<(n4 + 255) / 256, 256, 0, stream>>>((const float4*)x, dis, (uint2*)zh0, n4);

    const float4* h0 = (const float4*)x;
    int grid = (N_NODES + 3) / 4;
    // it1: zh0 -> zb0 ; it2: zb0 -> zb1 (stage dead by then) ; ... ; it5 -> d_out
    spmm_k<false><<<grid, 256, 0, stream>>>((const uint4*)zh0, (const uint4*)zh0, h0, zb0,   rowstart, col, dis, N_NODES);
    spmm_k<false><<<grid, 256, 0, stream>>>((const uint4*)zb0, (const uint4*)zh0, h0, zb1,   rowstart, col, dis, N_NODES);
    spmm_k<false><<<grid, 256, 0, stream>>>((const uint4*)zb1, (const uint4*)zh0, h0, zb0,   rowstart, col, dis, N_NODES);
    spmm_k<false><<<grid, 256, 0, stream>>>((const uint4*)zb0, (const uint4*)zh0, h0, zb1,   rowstart, col, dis, N_NODES);
    spmm_k<true ><<<grid, 256, 0, stream>>>((const uint4*)zb1, (const uint4*)zh0, h0, d_out, rowstart, col, dis, N_NODES);
}

// Round 6
// 394.508 us; speedup vs baseline: 2.6183x; 1.0592x over previous
//
#include <hip/hip_runtime.h>

// APPNP: K=5 iterations of x = 0.2 * Ahat * x + 0.8 * h0.
// R6: (a) spmm accumulates in packed float2 (v_pk_add_f32) -> ~25% fewer VALU
// insts in the VALU-bound gather loop (R5: VALUBusy=69%); (b) ndeg+bin2 merged
// into build_k (1 block/bucket, LDS hist+scan+cursors) -> kills bin2's 4x
// stage re-read. spmm FETCH=8 XCD x 12.8MB is the structural gather floor.
#define N_NODES 100000
#define N_EDGES 1600000
#define D_FEAT  64
#define ALPHA_C 0.8f
#define BETA_C  0.2f

#define BSHIFT  10                                   // 1024 nodes per bucket
#define NBUCK   ((N_NODES + 1023) >> BSHIFT)         // 98

typedef __attribute__((ext_vector_type(2))) float f32x2;

// ---------------- CSR build ----------------

// per-bucket edge counts: LDS histogram, one global atomic per (block,bucket)
__global__ __launch_bounds__(256) void bcount_k(const int* __restrict__ dst,
                                                int* __restrict__ bcnt, int E) {
    __shared__ int cnt[NBUCK];
    int t = threadIdx.x;
    for (int i = t; i < NBUCK; i += 256) cnt[i] = 0;
    __syncthreads();
    int base = blockIdx.x * 2048;
    #pragma unroll
    for (int i = 0; i < 8; ++i) {
        int e = base + t + i * 256;
        if (e < E) atomicAdd(&cnt[dst[e] >> BSHIFT], 1);
    }
    __syncthreads();
    for (int i = t; i < NBUCK; i += 256)
        if (cnt[i]) atomicAdd(&bcnt[i], cnt[i]);
}

// single-block exclusive scan of bucket counts -> bucket bases + bin1 cursors
__global__ void bscan_k(const int* __restrict__ bcnt, int* __restrict__ bbase,
                        int* __restrict__ gcur) {
    __shared__ int sh[128];
    int t = threadIdx.x;                 // 128 threads
    int v = (t < NBUCK) ? bcnt[t] : 0;
    sh[t] = v;
    __syncthreads();
    for (int off = 1; off < 128; off <<= 1) {
        int y = (t >= off) ? sh[t - off] : 0;
        __syncthreads();
        if (t >= off) sh[t] += y;
        __syncthreads();
    }
    if (t < NBUCK) {
        int ex = sh[t] - v;
        bbase[t] = ex;
        gcur[t]  = ex;
    }
    if (t == NBUCK - 1) bbase[NBUCK] = sh[t];
}

// bin edges by dst-bucket into bucket-major staging (~170B contiguous runs)
__global__ __launch_bounds__(256) void bin1_k(
    const int* __restrict__ src, const int* __restrict__ dst,
    int* __restrict__ gcur, uint2* __restrict__ stage, int E) {
    __shared__ int cnt[NBUCK];
    __shared__ int gbase[NBUCK];
    int t = threadIdx.x;
    for (int i = t; i < NBUCK; i += 256) cnt[i] = 0;
    __syncthreads();
    int base = blockIdx.x * 2048;
    int s[8], d[8], r[8];
    #pragma unroll
    for (int i = 0; i < 8; ++i) {
        int e = base + t + i * 256;
        if (e < E) {
            s[i] = src[e];
            d[i] = dst[e];
            r[i] = atomicAdd(&cnt[d[i] >> BSHIFT], 1);
        }
    }
    __syncthreads();
    for (int i = t; i < NBUCK; i += 256)
        if (cnt[i]) gbase[i] = atomicAdd(&gcur[i], cnt[i]);
    __syncthreads();
    #pragma unroll
    for (int i = 0; i < 8; ++i) {
        int e = base + t + i * 256;
        if (e < E) {
            int b = d[i] >> BSHIFT;
            stage[gbase[b] + r[i]] = make_uint2((unsigned)s[i], (unsigned)d[i]);
        }
    }
}

// one block per bucket: LDS degree hist -> LDS scan -> rowstart/dis writes ->
// scatter col with LDS cursors (replaces ndeg_k + bin2_k; stage read 2x but
// 2nd pass hits L2; col scatter window 64KB = full-line writebacks).
__global__ __launch_bounds__(512) void build_k(
    const uint2* __restrict__ stage, const int* __restrict__ bbase,
    float* __restrict__ dis, int* __restrict__ rowstart,
    int* __restrict__ col, int N) {
    __shared__ int degl[1024];
    __shared__ int part[512];
    __shared__ int cur[1024];
    int b = blockIdx.x, t = threadIdx.x;
    int nlo = b << BSHIFT;
    degl[t] = 0; degl[t + 512] = 0;
    __syncthreads();
    int slo = bbase[b], shi = bbase[b + 1];
    for (int j = slo + t; j < shi; j += 512)
        atomicAdd(&degl[(int)stage[j].y - nlo], 1);
    __syncthreads();
    int s0 = degl[2 * t], s1 = degl[2 * t + 1];
    int c1 = s0 + s1;
    part[t] = c1;
    __syncthreads();
    for (int off = 1; off < 512; off <<= 1) {
        int y = (t >= off) ? part[t - off] : 0;
        __syncthreads();
        if (t >= off) part[t] += y;
        __syncthreads();
    }
    int pre = part[t] - c1 + slo;        // exclusive prefix + global base
    int n0 = nlo + 2 * t;
    if (n0     <= N) rowstart[n0]     = pre;
    if (n0 + 1 <= N) rowstart[n0 + 1] = pre + s0;
    if (n0     < N) dis[n0]     = rsqrtf((float)(s0 + 1));
    if (n0 + 1 < N) dis[n0 + 1] = rsqrtf((float)(s1 + 1));
    cur[2 * t]     = pre;
    cur[2 * t + 1] = pre + s0;
    __syncthreads();
    for (int j = slo + t; j < shi; j += 512) {
        uint2 e = stage[j];
        int p = atomicAdd(&cur[(int)e.y - nlo], 1);
        col[p] = (int)e.x;
    }
}

// ---------------- bf16 helpers ----------------

__device__ inline unsigned pack_bf16_rne(float a, float b) {
    unsigned ua = __float_as_uint(a);
    unsigned ub = __float_as_uint(b);
    ua = (ua + 0x7FFFu + ((ua >> 16) & 1u)) >> 16;
    ub = (ub + 0x7FFFu + ((ub >> 16) & 1u)) >> 16;
    return ua | (ub << 16);
}

// unpack 8 bf16 and accumulate into 4 packed-f32 accumulators (v_pk_add_f32)
__device__ inline void bf16x8_add2(const uint4 u, f32x2* acc) {
    f32x2 p0, p1, p2, p3;
    p0.x = __uint_as_float(u.x << 16); p0.y = __uint_as_float(u.x & 0xFFFF0000u);
    p1.x = __uint_as_float(u.y << 16); p1.y = __uint_as_float(u.y & 0xFFFF0000u);
    p2.x = __uint_as_float(u.z << 16); p2.y = __uint_as_float(u.z & 0xFFFF0000u);
    p3.x = __uint_as_float(u.w << 16); p3.y = __uint_as_float(u.w & 0xFFFF0000u);
    acc[0] += p0; acc[1] += p1; acc[2] += p2; acc[3] += p3;
}

// zh0 = dis .* x, packed bf16 (also the seed iterate z0)
__global__ void cvt_k(const float4* __restrict__ x4, const float* __restrict__ dis,
                      uint2* __restrict__ zh, int n4) {
    int t = blockIdx.x * blockDim.x + threadIdx.x;
    if (t < n4) {
        float dd = dis[t >> 4];
        float4 v = x4[t];
        uint2 o;
        o.x = pack_bf16_rne(dd * v.x, dd * v.y);
        o.y = pack_bf16_rne(dd * v.z, dd * v.w);
        zh[t] = o;
    }
}

// ---------------- propagation (z-space) ----------------
// One wave per row; slot = lane>>3 (8 neighbor slots), f = lane&7 (16B of the
// 128B bf16 row). acc = sum of z over N+(row). Intermediate iterations emit
// bf16 z' = 0.2*dis^2*acc + 0.8*zh0; final emits fp32 x = 0.2*dis*acc + 0.8*h0.
template <bool FINAL>
__global__ __launch_bounds__(256) void spmm_k(
    const uint4* __restrict__ zin, const uint4* __restrict__ zh0,
    const float4* __restrict__ h04, void* __restrict__ out_,
    const int* __restrict__ rowstart, const int* __restrict__ col,
    const float* __restrict__ dis, int N) {
    int row = blockIdx.x * 4 + (threadIdx.x >> 6);
    if (row >= N) return;
    int lane = threadIdx.x & 63;
    int slot = lane >> 3;
    int f    = lane & 7;

    int s = rowstart[row];
    int e = rowstart[row + 1];

    f32x2 acc0[4] = {{0,0},{0,0},{0,0},{0,0}};
    f32x2 acc1[4] = {{0,0},{0,0},{0,0},{0,0}};

    int jj = s + slot;
    for (; jj + 8 < e; jj += 16) {
        int c0 = col[jj];
        int c1 = col[jj + 8];
        uint4 a = zin[(size_t)c0 * 8 + f];
        uint4 b = zin[(size_t)c1 * 8 + f];
        bf16x8_add2(a, acc0);
        bf16x8_add2(b, acc1);
    }
    if (jj < e) {
        uint4 a = zin[(size_t)col[jj] * 8 + f];
        bf16x8_add2(a, acc0);
    }
    #pragma unroll
    for (int i = 0; i < 4; ++i) acc0[i] += acc1[i];

    if (slot == 0) {                       // self-loop term, counted once
        uint4 sx = zin[(size_t)row * 8 + f];
        bf16x8_add2(sx, acc0);
    }

    #pragma unroll
    for (int m = 8; m <= 32; m <<= 1) {
        #pragma unroll
        for (int i = 0; i < 4; ++i) {
            acc0[i].x += __shfl_xor(acc0[i].x, m);
            acc0[i].y += __shfl_xor(acc0[i].y, m);
        }
    }

    float accf[8];
    #pragma unroll
    for (int i = 0; i < 4; ++i) { accf[2 * i] = acc0[i].x; accf[2 * i + 1] = acc0[i].y; }

    float dd = dis[row];
    if (FINAL) {
        if (slot < 2) {
            float w = BETA_C * dd;
            int chunk = f * 2 + slot;
            int b = slot * 4;
            float4 h = h04[(size_t)row * 16 + chunk];
            float4 o;
            o.x = ALPHA_C * h.x + w * accf[b + 0];
            o.y = ALPHA_C * h.y + w * accf[b + 1];
            o.z = ALPHA_C * h.z + w * accf[b + 2];
            o.w = ALPHA_C * h.w + w * accf[b + 3];
            ((float4*)out_)[(size_t)row * 16 + chunk] = o;
        }
    } else {
        if (slot == 0) {
            float w = BETA_C * dd * dd;
            uint4 zh = zh0[(size_t)row * 8 + f];
            float hf[8];
            hf[0] = __uint_as_float(zh.x << 16);
            hf[1] = __uint_as_float(zh.x & 0xFFFF0000u);
            hf[2] = __uint_as_float(zh.y << 16);
            hf[3] = __uint_as_float(zh.y & 0xFFFF0000u);
            hf[4] = __uint_as_float(zh.z << 16);
            hf[5] = __uint_as_float(zh.z & 0xFFFF0000u);
            hf[6] = __uint_as_float(zh.w << 16);
            hf[7] = __uint_as_float(zh.w & 0xFFFF0000u);
            uint4 st;
            st.x = pack_bf16_rne(w * accf[0] + ALPHA_C * hf[0],
                                 w * accf[1] + ALPHA_C * hf[1]);
            st.y = pack_bf16_rne(w * accf[2] + ALPHA_C * hf[2],
                                 w * accf[3] + ALPHA_C * hf[3]);
            st.z = pack_bf16_rne(w * accf[4] + ALPHA_C * hf[4],
                                 w * accf[5] + ALPHA_C * hf[5]);
            st.w = pack_bf16_rne(w * accf[6] + ALPHA_C * hf[6],
                                 w * accf[7] + ALPHA_C * hf[7]);
            ((uint4*)out_)[(size_t)row * 8 + f] = st;
        }
    }
}

// ---------------- launch ----------------

extern "C" void kernel_launch(void* const* d_in, const int* in_sizes, int n_in,
                              void* d_out, int out_size, void* d_ws, size_t ws_size,
                              hipStream_t stream) {
    const float* x   = (const float*)d_in[0];
    const int*   ei  = (const int*)d_in[1];
    const int*   src = ei;            // edge_index[0]
    const int*   dst = ei + N_EDGES;  // edge_index[1]

    char* ws = (char*)d_ws;
    size_t off = 0;
    auto alloc = [&](size_t bytes) -> void* {
        void* p = ws + off;
        off = (off + bytes + 255) & ~(size_t)255;
        return p;
    };
    int*   bcnt     = (int*)  alloc((size_t)NBUCK * 4);
    int*   bbase    = (int*)  alloc((size_t)(NBUCK + 1) * 4);
    int*   gcur     = (int*)  alloc((size_t)NBUCK * 4);
    int*   rowstart = (int*)  alloc((size_t)(N_NODES + 1) * 4);
    float* dis      = (float*)alloc((size_t)N_NODES * 4);
    int*   col      = (int*)  alloc((size_t)N_EDGES * 4);
    void*  zh0      = alloc((size_t)N_NODES * D_FEAT * 2);   // dis.*h0 bf16
    void*  zb0      = alloc((size_t)N_NODES * D_FEAT * 2);   // z iterate
    void*  zb1      = alloc((size_t)N_NODES * D_FEAT * 2);   // z iterate; first
                                                             // written at it2,
                                                             // stage dead by then
    uint2* stage    = (uint2*)zb1;   // aliased: 12.8MB staging (E*8 == N*64*2)

    hipMemsetAsync(bcnt, 0, (size_t)NBUCK * 4, stream);

    int eb2 = (N_EDGES + 2047) / 2048;
    bcount_k<<<eb2, 256, 0, stream>>>(dst, bcnt, N_EDGES);
    bscan_k <<<1, 128, 0, stream>>>(bcnt, bbase, gcur);
    bin1_k  <<<eb2, 256, 0, stream>>>(src, dst, gcur, stage, N_EDGES);
    build_k <<<NBUCK, 512, 0, stream>>>(stage, bbase, dis, rowstart, col, N_NODES);

    int n4 = N_NODES * D_FEAT / 4;
    cvt_k<<<(n4 + 255) / 256, 256, 0, stream>>>((const float4*)x, dis, (uint2*)zh0, n4);

    const float4* h0 = (const float4*)x;
    int grid = (N_NODES + 3) / 4;
    // it1: zh0 -> zb0 ; it2: zb0 -> zb1 (stage dead by then) ; ... ; it5 -> d_out
    spmm_k<false><<<grid, 256, 0, stream>>>((const uint4*)zh0, (const uint4*)zh0, h0, zb0,   rowstart, col, dis, N_NODES);
    spmm_k<false><<<grid, 256, 0, stream>>>((const uint4*)zb0, (const uint4*)zh0, h0, zb1,   rowstart, col, dis, N_NODES);
    spmm_k<false><<<grid, 256, 0, stream>>>((const uint4*)zb1, (const uint4*)zh0, h0, zb0,   rowstart, col, dis, N_NODES);
    spmm_k<false><<<grid, 256, 0, stream>>>((const uint4*)zb0, (const uint4*)zh0, h0, zb1,   rowstart, col, dis, N_NODES);
    spmm_k<true ><<<grid, 256, 0, stream>>>((const uint4*)zb1, (const uint4*)zh0, h0, d_out, rowstart, col, dis, N_NODES);
}

// Round 7
// 361.461 us; speedup vs baseline: 2.8577x; 1.0914x over previous
//
#include <hip/hip_runtime.h>

// APPNP: K=5 iterations of x = 0.2 * Ahat * x + 0.8 * h0.
// R7: spmm restructured 4 rows/wave, lane = 4 feats (uint2 of bf16) -> no
// cross-lane reduce, no slot conditionals, 4x fewer waves. R6 evidence:
// per-row fixed overhead (~100 wave-insts: butterfly shfl + epilogue) was
// ~3x the gather-loop work at mean degree 16.
#define N_NODES 100000
#define N_EDGES 1600000
#define D_FEAT  64
#define ALPHA_C 0.8f
#define BETA_C  0.2f

#define BSHIFT  10                                   // 1024 nodes per bucket
#define NBUCK   ((N_NODES + 1023) >> BSHIFT)         // 98

typedef __attribute__((ext_vector_type(2))) float f32x2;

// ---------------- CSR build ----------------

// per-bucket edge counts: LDS histogram, one global atomic per (block,bucket)
__global__ __launch_bounds__(256) void bcount_k(const int* __restrict__ dst,
                                                int* __restrict__ bcnt, int E) {
    __shared__ int cnt[NBUCK];
    int t = threadIdx.x;
    for (int i = t; i < NBUCK; i += 256) cnt[i] = 0;
    __syncthreads();
    int base = blockIdx.x * 2048;
    #pragma unroll
    for (int i = 0; i < 8; ++i) {
        int e = base + t + i * 256;
        if (e < E) atomicAdd(&cnt[dst[e] >> BSHIFT], 1);
    }
    __syncthreads();
    for (int i = t; i < NBUCK; i += 256)
        if (cnt[i]) atomicAdd(&bcnt[i], cnt[i]);
}

// single-block exclusive scan of bucket counts -> bucket bases + bin1 cursors
__global__ void bscan_k(const int* __restrict__ bcnt, int* __restrict__ bbase,
                        int* __restrict__ gcur) {
    __shared__ int sh[128];
    int t = threadIdx.x;                 // 128 threads
    int v = (t < NBUCK) ? bcnt[t] : 0;
    sh[t] = v;
    __syncthreads();
    for (int off = 1; off < 128; off <<= 1) {
        int y = (t >= off) ? sh[t - off] : 0;
        __syncthreads();
        if (t >= off) sh[t] += y;
        __syncthreads();
    }
    if (t < NBUCK) {
        int ex = sh[t] - v;
        bbase[t] = ex;
        gcur[t]  = ex;
    }
    if (t == NBUCK - 1) bbase[NBUCK] = sh[t];
}

// bin edges by dst-bucket into bucket-major staging (~170B contiguous runs)
__global__ __launch_bounds__(256) void bin1_k(
    const int* __restrict__ src, const int* __restrict__ dst,
    int* __restrict__ gcur, uint2* __restrict__ stage, int E) {
    __shared__ int cnt[NBUCK];
    __shared__ int gbase[NBUCK];
    int t = threadIdx.x;
    for (int i = t; i < NBUCK; i += 256) cnt[i] = 0;
    __syncthreads();
    int base = blockIdx.x * 2048;
    int s[8], d[8], r[8];
    #pragma unroll
    for (int i = 0; i < 8; ++i) {
        int e = base + t + i * 256;
        if (e < E) {
            s[i] = src[e];
            d[i] = dst[e];
            r[i] = atomicAdd(&cnt[d[i] >> BSHIFT], 1);
        }
    }
    __syncthreads();
    for (int i = t; i < NBUCK; i += 256)
        if (cnt[i]) gbase[i] = atomicAdd(&gcur[i], cnt[i]);
    __syncthreads();
    #pragma unroll
    for (int i = 0; i < 8; ++i) {
        int e = base + t + i * 256;
        if (e < E) {
            int b = d[i] >> BSHIFT;
            stage[gbase[b] + r[i]] = make_uint2((unsigned)s[i], (unsigned)d[i]);
        }
    }
}

// one block per bucket: LDS degree hist -> LDS scan -> rowstart/dis writes ->
// scatter col with LDS cursors (stage read 2x, 2nd pass from L2; col scatter
// window 64KB = full-line writebacks).
__global__ __launch_bounds__(512) void build_k(
    const uint2* __restrict__ stage, const int* __restrict__ bbase,
    float* __restrict__ dis, int* __restrict__ rowstart,
    int* __restrict__ col, int N) {
    __shared__ int degl[1024];
    __shared__ int part[512];
    __shared__ int cur[1024];
    int b = blockIdx.x, t = threadIdx.x;
    int nlo = b << BSHIFT;
    degl[t] = 0; degl[t + 512] = 0;
    __syncthreads();
    int slo = bbase[b], shi = bbase[b + 1];
    for (int j = slo + t; j < shi; j += 512)
        atomicAdd(&degl[(int)stage[j].y - nlo], 1);
    __syncthreads();
    int s0 = degl[2 * t], s1 = degl[2 * t + 1];
    int c1 = s0 + s1;
    part[t] = c1;
    __syncthreads();
    for (int off = 1; off < 512; off <<= 1) {
        int y = (t >= off) ? part[t - off] : 0;
        __syncthreads();
        if (t >= off) part[t] += y;
        __syncthreads();
    }
    int pre = part[t] - c1 + slo;        // exclusive prefix + global base
    int n0 = nlo + 2 * t;
    if (n0     <= N) rowstart[n0]     = pre;
    if (n0 + 1 <= N) rowstart[n0 + 1] = pre + s0;
    if (n0     < N) dis[n0]     = rsqrtf((float)(s0 + 1));
    if (n0 + 1 < N) dis[n0 + 1] = rsqrtf((float)(s1 + 1));
    cur[2 * t]     = pre;
    cur[2 * t + 1] = pre + s0;
    __syncthreads();
    for (int j = slo + t; j < shi; j += 512) {
        uint2 e = stage[j];
        int p = atomicAdd(&cur[(int)e.y - nlo], 1);
        col[p] = (int)e.x;
    }
}

// ---------------- bf16 helpers ----------------

__device__ inline unsigned pack_bf16_rne(float a, float b) {
    unsigned ua = __float_as_uint(a);
    unsigned ub = __float_as_uint(b);
    ua = (ua + 0x7FFFu + ((ua >> 16) & 1u)) >> 16;
    ub = (ub + 0x7FFFu + ((ub >> 16) & 1u)) >> 16;
    return ua | (ub << 16);
}

// unpack 4 bf16 (uint2) and accumulate into 2 packed-f32 accumulators
__device__ inline void bf16x4_add2(const uint2 u, f32x2* acc) {
    f32x2 p0, p1;
    p0.x = __uint_as_float(u.x << 16); p0.y = __uint_as_float(u.x & 0xFFFF0000u);
    p1.x = __uint_as_float(u.y << 16); p1.y = __uint_as_float(u.y & 0xFFFF0000u);
    acc[0] += p0; acc[1] += p1;
}

// zh0 = dis .* x, packed bf16 (also the seed iterate z0)
__global__ void cvt_k(const float4* __restrict__ x4, const float* __restrict__ dis,
                      uint2* __restrict__ zh, int n4) {
    int t = blockIdx.x * blockDim.x + threadIdx.x;
    if (t < n4) {
        float dd = dis[t >> 4];
        float4 v = x4[t];
        uint2 o;
        o.x = pack_bf16_rne(dd * v.x, dd * v.y);
        o.y = pack_bf16_rne(dd * v.z, dd * v.w);
        zh[t] = o;
    }
}

// ---------------- propagation (z-space) ----------------
// 4 rows per wave: quarter q = lane>>4 owns a row, f = lane&15 owns feats
// [4f..4f+3] as one uint2 (4 bf16). Each lane privately accumulates its 4
// feats over the row's neighbors -> no cross-lane reduce. Gathers are 128B
// contiguous per quarter. Divergence cost: max-degree over 4 rows (~25%).
template <bool FINAL>
__global__ __launch_bounds__(256) void spmm_k(
    const uint2* __restrict__ zin, const uint2* __restrict__ zh0,
    const float4* __restrict__ h04, void* __restrict__ out_,
    const int* __restrict__ rowstart, const int* __restrict__ col,
    const float* __restrict__ dis, int N) {
    int lane = threadIdx.x & 63;
    int wid  = threadIdx.x >> 6;
    int q    = lane >> 4;
    int f    = lane & 15;
    int row  = (blockIdx.x * 4 + wid) * 4 + q;
    if (row >= N) return;

    int s = rowstart[row];
    int e = rowstart[row + 1];

    f32x2 acc0[2] = {{0,0},{0,0}};
    f32x2 acc1[2] = {{0,0},{0,0}};

    int j = s;
    for (; j + 1 < e; j += 2) {
        int c0 = col[j];
        int c1 = col[j + 1];
        uint2 a = zin[(size_t)c0 * 16 + f];
        uint2 b = zin[(size_t)c1 * 16 + f];
        bf16x4_add2(a, acc0);
        bf16x4_add2(b, acc1);
    }
    if (j < e) {
        uint2 a = zin[(size_t)col[j] * 16 + f];
        bf16x4_add2(a, acc0);
    }
    acc0[0] += acc1[0];
    acc0[1] += acc1[1];

    // self-loop: z_row enters the sum with weight 1
    uint2 sz = zin[(size_t)row * 16 + f];
    bf16x4_add2(sz, acc0);

    float dd = dis[row];
    if (FINAL) {
        float w = BETA_C * dd;
        float4 h = h04[(size_t)row * 16 + f];
        float4 o;
        o.x = ALPHA_C * h.x + w * acc0[0].x;
        o.y = ALPHA_C * h.y + w * acc0[0].y;
        o.z = ALPHA_C * h.z + w * acc0[1].x;
        o.w = ALPHA_C * h.w + w * acc0[1].y;
        ((float4*)out_)[(size_t)row * 16 + f] = o;
    } else {
        float w = BETA_C * dd * dd;
        uint2 zh = zh0[(size_t)row * 16 + f];
        float h0a = __uint_as_float(zh.x << 16);
        float h0b = __uint_as_float(zh.x & 0xFFFF0000u);
        float h1a = __uint_as_float(zh.y << 16);
        float h1b = __uint_as_float(zh.y & 0xFFFF0000u);
        uint2 st;
        st.x = pack_bf16_rne(w * acc0[0].x + ALPHA_C * h0a,
                             w * acc0[0].y + ALPHA_C * h0b);
        st.y = pack_bf16_rne(w * acc0[1].x + ALPHA_C * h1a,
                             w * acc0[1].y + ALPHA_C * h1b);
        ((uint2*)out_)[(size_t)row * 16 + f] = st;
    }
}

// ---------------- launch ----------------

extern "C" void kernel_launch(void* const* d_in, const int* in_sizes, int n_in,
                              void* d_out, int out_size, void* d_ws, size_t ws_size,
                              hipStream_t stream) {
    const float* x   = (const float*)d_in[0];
    const int*   ei  = (const int*)d_in[1];
    const int*   src = ei;            // edge_index[0]
    const int*   dst = ei + N_EDGES;  // edge_index[1]

    char* ws = (char*)d_ws;
    size_t off = 0;
    auto alloc = [&](size_t bytes) -> void* {
        void* p = ws + off;
        off = (off + bytes + 255) & ~(size_t)255;
        return p;
    };
    int*   bcnt     = (int*)  alloc((size_t)NBUCK * 4);
    int*   bbase    = (int*)  alloc((size_t)(NBUCK + 1) * 4);
    int*   gcur     = (int*)  alloc((size_t)NBUCK * 4);
    int*   rowstart = (int*)  alloc((size_t)(N_NODES + 1) * 4);
    float* dis      = (float*)alloc((size_t)N_NODES * 4);
    int*   col      = (int*)  alloc((size_t)N_EDGES * 4);
    void*  zh0      = alloc((size_t)N_NODES * D_FEAT * 2);   // dis.*h0 bf16
    void*  zb0      = alloc((size_t)N_NODES * D_FEAT * 2);   // z iterate
    void*  zb1      = alloc((size_t)N_NODES * D_FEAT * 2);   // z iterate; first
                                                             // written at it2,
                                                             // stage dead by then
    uint2* stage    = (uint2*)zb1;   // aliased: 12.8MB staging (E*8 == N*64*2)

    hipMemsetAsync(bcnt, 0, (size_t)NBUCK * 4, stream);

    int eb2 = (N_EDGES + 2047) / 2048;
    bcount_k<<<eb2, 256, 0, stream>>>(dst, bcnt, N_EDGES);
    bscan_k <<<1, 128, 0, stream>>>(bcnt, bbase, gcur);
    bin1_k  <<<eb2, 256, 0, stream>>>(src, dst, gcur, stage, N_EDGES);
    build_k <<<NBUCK, 512, 0, stream>>>(stage, bbase, dis, rowstart, col, N_NODES);

    int n4 = N_NODES * D_FEAT / 4;
    cvt_k<<<(n4 + 255) / 256, 256, 0, stream>>>((const float4*)x, dis, (uint2*)zh0, n4);

    const float4* h0 = (const float4*)x;
    int grid = (N_NODES + 15) / 16;      // 16 rows per 256-thread block
    // it1: zh0 -> zb0 ; it2: zb0 -> zb1 (stage dead by then) ; ... ; it5 -> d_out
    spmm_k<false><<<grid, 256, 0, stream>>>((const uint2*)zh0, (const uint2*)zh0, h0, zb0,   rowstart, col, dis, N_NODES);
    spmm_k<false><<<grid, 256, 0, stream>>>((const uint2*)zb0, (const uint2*)zh0, h0, zb1,   rowstart, col, dis, N_NODES);
    spmm_k<false><<<grid, 256, 0, stream>>>((const uint2*)zb1, (const uint2*)zh0, h0, zb0,   rowstart, col, dis, N_NODES);
    spmm_k<false><<<grid, 256, 0, stream>>>((const uint2*)zb0, (const uint2*)zh0, h0, zb1,   rowstart, col, dis, N_NODES);
    spmm_k<true ><<<grid, 256, 0, stream>>>((const uint2*)zb1, (const uint2*)zh0, h0, d_out, rowstart, col, dis, N_NODES);
}